// Round 3
// baseline (790.016 us; speedup 1.0000x reference)
//
#include <hip/hip_runtime.h>
#include <hip/hip_cooperative_groups.h>

namespace cg = cooperative_groups;

#define HW_PIX (2160 * 3840)   // 8294400 pixels
#define QPIX   (HW_PIX / 4)    // 2073600 pixel-quads
#define D   33
#define D3  (33 * 33 * 33)     // 35937
#define M   (3 * D3)           // 107811 floats per (half, n) slice
#define MP  107812             // padded accum row stride (16B-aligned rows)
#define NLUT 350

// Paired-entry grid: idx[h][b][g][r], b,g,r in [0,32). Entry = TWO adjacent
// uint4 (32 B, one 64 B line): uint4 #0 = b-level b, #1 = b-level b+1.
// Each uint4 packs 12 values at 10 bits: word[k] = q[3k]|q[3k+1]<<10|q[3k+2]<<20,
// j = (gg*2+rr)*3+c.
#define PIDX  (32 * 32 * 32)       // 32768 entries per half
#define PU4   (PIDX * 2)           // uint4 count per half

#define CH    1024                 // floats per reduce tile
#define HT    ((M + CH - 1) / CH)  // 106 tiles per (split, half)
#define NSMAX 4

#define NB    1024                 // cooperative grid blocks (4/CU @ <=128 VGPR)
#define BLK   256
#define NT    (NB * BLK)

typedef float        f4  __attribute__((ext_vector_type(4)));
typedef unsigned int u4  __attribute__((ext_vector_type(4)));
typedef float        f4u __attribute__((ext_vector_type(4), aligned(4)));

// ---------------------------------------------------------------------------
// Phase 1 tile: partial[s][h][vb..vb+CH) = sum over split-s n's of lut slices.
// Waves own disjoint 256-float chunks -> no LDS, no intra-block sync.
// Inner loop: 1 dwordx4 load + 4 v_add_f32 + SGPR slice bump per n.
// ---------------------------------------------------------------------------
__device__ __forceinline__ void reduce_tile(const float* __restrict__ lut,
                                            float* __restrict__ accum,
                                            int tile, int ns)
{
    const int s  = tile / (2 * HT);
    const int rm = tile - s * (2 * HT);
    const int h  = rm / HT;
    const int ti = rm - h * HT;
    const int vb = ti * CH;

    const int cbase = NLUT / ns, crem = NLUT % ns;     // 87 r2 (ns=4) | 350 r0
    const int start = s * cbase + min(s, crem);
    const int count = cbase + (s < crem ? 1 : 0);

    const float* __restrict__ base = lut + ((long long)h * NLUT + start) * M;
    float* __restrict__ arow = accum + (long long)(s * 2 + h) * MP;

    if (vb + CH <= M) {
        const int idx = vb + ((threadIdx.x >> 6) << 8) + ((threadIdx.x & 63) << 2);
        const float* p = base + idx;
        f4 a = {0.f, 0.f, 0.f, 0.f};
        #pragma unroll 4
        for (int n = 0; n < count; ++n, p += M)
            a += *(const f4u*)p;
        *(f4*)(arow + idx) = a;                        // row + idx are 16B-aligned
    } else {
        // tail tile (291 floats): scalar per-element
        for (int e = vb + (int)threadIdx.x; e < M; e += BLK) {
            const float* p = base + e;
            float a = 0.f;
            for (int n = 0; n < count; ++n, p += M) a += *p;
            arow[e] = a;
        }
    }
}

// ---------------------------------------------------------------------------
// Phase 2: sum ns partials, quantize to 10 bit, pack paired 32 B entries.
// ---------------------------------------------------------------------------
__device__ __forceinline__ void pack_entry(const float* __restrict__ accum,
                                           uint4* __restrict__ packed,
                                           int t, int ns)
{
    const int h = t >> 15;
    const int e = t & (PIDX - 1);
    const int b = e >> 10;
    const int g = (e >> 5) & 31;
    const int r = e & 31;

    const float* A = accum + (long long)h * MP;        // split s at + s*2*MP
    uint4 E[2];
    #pragma unroll
    for (int bb = 0; bb < 2; ++bb) {
        unsigned q[12];
        int j = 0;
        #pragma unroll
        for (int gg = 0; gg < 2; ++gg)
            #pragma unroll
            for (int rr = 0; rr < 2; ++rr)
                #pragma unroll
                for (int c = 0; c < 3; ++c) {
                    int i = c * D3 + ((b + bb) * D + (g + gg)) * D + (r + rr);
                    float v = 0.f;
                    for (int s = 0; s < ns; ++s) v += A[i + (long long)s * 2 * MP];
                    v = fminf(fmaxf(v, 0.0f), 1.0f);
                    q[j++] = (unsigned)(v * 1023.0f + 0.5f);
                }
        E[bb].x = q[0] | (q[1]  << 10) | (q[2]  << 20);
        E[bb].y = q[3] | (q[4]  << 10) | (q[5]  << 20);
        E[bb].z = q[6] | (q[7]  << 10) | (q[8]  << 20);
        E[bb].w = q[9] | (q[10] << 10) | (q[11] << 20);
    }
    packed[2 * t]     = E[0];
    packed[2 * t + 1] = E[1];
}

// ---------------------------------------------------------------------------
// Trilinear apply for 4 independent pixels: all 8 gathers (one 64 B line per
// pixel) issued before any unpack -> 8 loads in flight per dependent stage.
// ---------------------------------------------------------------------------
__device__ __forceinline__ void apply4(const u4* __restrict__ L,
                                       const float* r, const float* g, const float* b,
                                       float* pr, float* pg, float* pb)
{
    u4 E0[4], E1[4];
    float fr[4], fg[4], fb[4];
    #pragma unroll
    for (int i = 0; i < 4; ++i) {
        float xr = r[i] * 32.0f, xg = g[i] * 32.0f, xb = b[i] * 32.0f;
        int r0 = min(max((int)xr, 0), 31);   // inputs >= 0: trunc == floor
        int g0 = min(max((int)xg, 0), 31);
        int b0 = min(max((int)xb, 0), 31);
        fr[i] = xr - (float)r0;
        fg[i] = xg - (float)g0;
        fb[i] = xb - (float)b0;
        int idx = (b0 << 10) + (g0 << 5) + r0;
        E0[i] = L[2 * idx];          // b-level b0
        E1[i] = L[2 * idx + 1];      // b-level b0+1 (same 64 B line)
    }
    const float inv = 1.0f / 1023.0f;
    #pragma unroll
    for (int i = 0; i < 4; ++i) {
        float w00 = (1.0f - fg[i]) * (1.0f - fr[i]);
        float w01 = (1.0f - fg[i]) * fr[i];
        float w10 = fg[i] * (1.0f - fr[i]);
        float w11 = fg[i] * fr[i];
        float wb0 = 1.0f - fb[i], wb1 = fb[i];

        float sr, sg, sb;
        {
            float a00 = wb0 * w00, a01 = wb0 * w01, a10 = wb0 * w10, a11 = wb0 * w11;
            sr = a00 * (float)( E0[i].x        & 1023) + a01 * (float)( E0[i].y        & 1023)
               + a10 * (float)( E0[i].z        & 1023) + a11 * (float)( E0[i].w        & 1023);
            sg = a00 * (float)((E0[i].x >> 10) & 1023) + a01 * (float)((E0[i].y >> 10) & 1023)
               + a10 * (float)((E0[i].z >> 10) & 1023) + a11 * (float)((E0[i].w >> 10) & 1023);
            sb = a00 * (float)((E0[i].x >> 20) & 1023) + a01 * (float)((E0[i].y >> 20) & 1023)
               + a10 * (float)((E0[i].z >> 20) & 1023) + a11 * (float)((E0[i].w >> 20) & 1023);
        }
        {
            float a00 = wb1 * w00, a01 = wb1 * w01, a10 = wb1 * w10, a11 = wb1 * w11;
            sr += a00 * (float)( E1[i].x        & 1023) + a01 * (float)( E1[i].y        & 1023)
                + a10 * (float)( E1[i].z        & 1023) + a11 * (float)( E1[i].w        & 1023);
            sg += a00 * (float)((E1[i].x >> 10) & 1023) + a01 * (float)((E1[i].y >> 10) & 1023)
                + a10 * (float)((E1[i].z >> 10) & 1023) + a11 * (float)((E1[i].w >> 10) & 1023);
            sb += a00 * (float)((E1[i].x >> 20) & 1023) + a01 * (float)((E1[i].y >> 20) & 1023)
                + a10 * (float)((E1[i].z >> 20) & 1023) + a11 * (float)((E1[i].w >> 20) & 1023);
        }
        pr[i] = sr * inv; pg[i] = sg * inv; pb[i] = sb * inv;
    }
}

__device__ __forceinline__ void apply_quad(const float* __restrict__ gt,
                                           const u4* __restrict__ packed,
                                           float* __restrict__ out, int q)
{
    const f4* g4 = (const f4*)gt;
    f4 Rv = __builtin_nontemporal_load(g4 + q);
    f4 Gv = __builtin_nontemporal_load(g4 + q + QPIX);
    f4 Bv = __builtin_nontemporal_load(g4 + q + 2 * QPIX);

    float r0[4] = {Rv.x, Rv.y, Rv.z, Rv.w};
    float g0[4] = {Gv.x, Gv.y, Gv.z, Gv.w};
    float b0[4] = {Bv.x, Bv.y, Bv.z, Bv.w};
    float r1[4], g1[4], b1[4], r2[4], g2[4], b2[4];

    apply4(packed,       r0, g0, b0, r1, g1, b1);
    apply4(packed + PU4, r1, g1, b1, r2, g2, b2);

    f4 Ro = {r2[0], r2[1], r2[2], r2[3]};
    f4 Go = {g2[0], g2[1], g2[2], g2[3]};
    f4 Bo = {b2[0], b2[1], b2[2], b2[3]};
    f4* o4 = (f4*)out;
    __builtin_nontemporal_store(Ro, o4 + q);
    __builtin_nontemporal_store(Go, o4 + q + QPIX);
    __builtin_nontemporal_store(Bo, o4 + q + 2 * QPIX);
}

// ---------------------------------------------------------------------------
// Single cooperative kernel: reduce -> sync -> pack -> sync -> fused apply.
// One dispatch = true pipeline duration visible in rocprof top-k.
// ---------------------------------------------------------------------------
__global__ __launch_bounds__(BLK, 4) void pipeline_kernel(
    const float* __restrict__ gt,
    const float* __restrict__ lut,
    float* __restrict__ accum,
    u4* __restrict__ packed,
    float* __restrict__ out)
{
    cg::grid_group grid = cg::this_grid();
    const int bid = blockIdx.x;

    // Phase 1: reduce (NS=4 -> 848 tiles over 1024 blocks, 1 tile each)
    if (bid < NSMAX * 2 * HT)
        reduce_tile(lut, accum, bid, NSMAX);
    grid.sync();

    // Phase 2: pack (65536 entries = first 256 blocks, 1 entry/thread)
    {
        int t = bid * BLK + (int)threadIdx.x;
        if (t < 2 * PIDX)
            pack_entry(accum, (uint4*)packed, t, NSMAX);
    }
    grid.sync();

    // Phase 3: fused double-apply, grid-stride over pixel-quads
    for (int q = bid * BLK + (int)threadIdx.x; q < QPIX; q += NT)
        apply_quad(gt, packed, out, q);
}

// ---------------------------------------------------------------------------
// Fallback path (non-cooperative), ns=1 compact layout.
// ---------------------------------------------------------------------------
__global__ __launch_bounds__(BLK) void reduce_fb(const float* __restrict__ lut,
                                                 float* __restrict__ accum)
{
    if (blockIdx.x < 2 * HT) reduce_tile(lut, accum, blockIdx.x, 1);
}

__global__ __launch_bounds__(BLK) void pack_fb(const float* __restrict__ accum,
                                               uint4* __restrict__ packed)
{
    int t = blockIdx.x * BLK + (int)threadIdx.x;
    if (t < 2 * PIDX) pack_entry(accum, packed, t, 1);
}

__global__ __launch_bounds__(BLK) void apply_fb(const float* __restrict__ gt,
                                                const u4* __restrict__ packed,
                                                float* __restrict__ out)
{
    int q = blockIdx.x * BLK + (int)threadIdx.x;
    if (q < QPIX) apply_quad(gt, packed, out, q);
}

extern "C" void kernel_launch(void* const* d_in, const int* in_sizes, int n_in,
                              void* d_out, int out_size, void* d_ws, size_t ws_size,
                              hipStream_t stream)
{
    const float* gt  = (const float*)d_in[0];
    const float* lut = (const float*)d_in[1];
    // d_in[2] / d_in[3] (L0, L1) are dead code in the reference.
    float* out = (float*)d_out;

    const size_t packed_bytes = (size_t)2 * PU4 * sizeof(uint4);          // 2 MiB
    const size_t a4 = (((size_t)NSMAX * 2 * MP * sizeof(float)) + 31) & ~(size_t)31; // 3.45 MB
    const size_t a1 = (((size_t)1     * 2 * MP * sizeof(float)) + 31) & ~(size_t)31; // 0.86 MB

    hipError_t e = hipErrorUnknown;
    if (ws_size >= a4 + packed_bytes) {
        float* accum  = (float*)d_ws;
        u4*    packed = (u4*)((char*)d_ws + a4);
        void* args[] = {(void*)&gt, (void*)&lut, (void*)&accum, (void*)&packed, (void*)&out};
        e = hipLaunchCooperativeKernel((const void*)pipeline_kernel,
                                       dim3(NB), dim3(BLK), args, 0, stream);
    }
    if (e != hipSuccess) {
        // Non-cooperative fallback, ns=1 (fits in ~2.96 MB of ws)
        float* accum  = (float*)d_ws;
        u4*    packed = (u4*)((char*)d_ws + a1);
        reduce_fb<<<dim3(2 * HT), dim3(BLK), 0, stream>>>(lut, accum);
        pack_fb<<<dim3((2 * PIDX + BLK - 1) / BLK), dim3(BLK), 0, stream>>>(accum, (uint4*)packed);
        apply_fb<<<dim3((QPIX + BLK - 1) / BLK), dim3(BLK), 0, stream>>>(gt, packed, out);
    }
}

// Round 4
// 534.207 us; speedup vs baseline: 1.4789x; 1.4789x over previous
//
#include <hip/hip_runtime.h>

#define HW_PIX (2160 * 3840)   // 8294400 pixels
#define QPIX   (HW_PIX / 4)    // 2073600 pixel-quads
#define D   33
#define D3  (33 * 33 * 33)     // 35937
#define M   (3 * D3)           // 107811 floats per (half, n) slice
#define NLUT 350
#define TWO_M (2 * M)          // 215622

// Paired-entry grid: idx[h][b][g][r], b,g,r in [0,32). Entry = TWO adjacent
// uint4 (32 B, one 64 B line): uint4 #0 = b-level b, #1 = b-level b+1.
// Each uint4 packs 12 values at 10 bits: word[k]=q[3k]|q[3k+1]<<10|q[3k+2]<<20,
// j = (gg*2+rr)*3+c.
#define PIDX  (32 * 32 * 32)       // 32768 entries per half
#define PU4   (PIDX * 2)           // uint4 count per half

#define HB     422                 // ceil(M/256) 256-output blocks per half

typedef float        f4 __attribute__((ext_vector_type(4)));
typedef unsigned int u4 __attribute__((ext_vector_type(4)));

// ---------------------------------------------------------------------------
// Kernel A: partial[s][h][v] = sum over n in split s of lut[h][n][v].
// NS=2: grid = 1688 blocks (6.6/CU, ~26 waves/CU). Wave w owns a 43/44-long
// n-chunk, split into TWO independent pointer chains x 4 offset streams =
// 8 independent accumulators -> up to 32 loads in flight per wave.
// lut is a 302 MB single-pass stream -> nontemporal (no L2 allocate).
// ---------------------------------------------------------------------------
template<int NS>
__global__ __launch_bounds__(256) void reduce_kernel(
    const float* __restrict__ lut,    // [2][NLUT][M]
    float* __restrict__ accum)        // [NS][2][M]
{
    const int lane = threadIdx.x & 63;
    const int w    = threadIdx.x >> 6;           // 0..3
    const int bid  = blockIdx.x;
    const int s    = bid / (2 * HB);             // n-split 0..NS-1
    const int rem  = bid - s * (2 * HB);
    const int h    = rem / HB;                   // half 0..1
    const int vb   = (rem - h * HB) * 256;       // within-half output base

    const int C = NLUT / NS;                     // 175 (NS=2) or 350
    const int q = C >> 2, r = C & 3;
    const int start = s * C + w * q + min(w, r);
    const int count = q + (w < r ? 1 : 0);       // 43..44 (NS=2)

    const float* __restrict__ hb =
        lut + ((long long)h * NLUT + start) * M; // wave-uniform

    int off[4];
    #pragma unroll
    for (int k = 0; k < 4; ++k) {
        int v = vb + lane + 64 * k;
        off[k] = (v < M) ? v : 0;                // clamp OOB lanes (store-masked)
    }

    // Two independent n-chains (cA over [0,c0), cB over [c0,count))
    const int c0 = count >> 1;
    float a0 = 0.f, a1 = 0.f, a2 = 0.f, a3 = 0.f;
    float b0 = 0.f, b1 = 0.f, b2 = 0.f, b3 = 0.f;
    {
        const float* pA = hb;
        const float* pB = hb + (long long)c0 * M;
        const int cB = count - c0;
        int n = 0;
        #pragma unroll 2
        for (; n < c0; ++n, pA += M, pB += M) {
            a0 += __builtin_nontemporal_load(pA + off[0]);
            a1 += __builtin_nontemporal_load(pA + off[1]);
            a2 += __builtin_nontemporal_load(pA + off[2]);
            a3 += __builtin_nontemporal_load(pA + off[3]);
            b0 += __builtin_nontemporal_load(pB + off[0]);
            b1 += __builtin_nontemporal_load(pB + off[1]);
            b2 += __builtin_nontemporal_load(pB + off[2]);
            b3 += __builtin_nontemporal_load(pB + off[3]);
        }
        if (cB > c0) {                           // odd count: one extra on B
            b0 += __builtin_nontemporal_load(pB + off[0]);
            b1 += __builtin_nontemporal_load(pB + off[1]);
            b2 += __builtin_nontemporal_load(pB + off[2]);
            b3 += __builtin_nontemporal_load(pB + off[3]);
        }
    }
    const float s0 = a0 + b0, s1 = a1 + b1, s2 = a2 + b2, s3 = a3 + b3;

    __shared__ float red[4][64][4];
    red[w][lane][0] = s0;
    red[w][lane][1] = s1;
    red[w][lane][2] = s2;
    red[w][lane][3] = s3;
    __syncthreads();

    const int o = threadIdx.x;
    const int v = vb + o;                        // o = 64*k + ln matches slot
    if (v < M) {
        int ln = o & 63, k = o >> 6;
        float t = (red[0][ln][k] + red[1][ln][k])
                + (red[2][ln][k] + red[3][ln][k]);
        accum[((long long)(s * 2 + h)) * M + v] = t;
    }
}

// ---------------------------------------------------------------------------
// Kernel B: sum the ns partials, quantize + pack into paired 32 B entries.
// ---------------------------------------------------------------------------
__global__ __launch_bounds__(256) void pack_kernel(
    const float* __restrict__ accum,  // [ns][2][M]
    uint4* __restrict__ packed,       // [2][PIDX][2]
    int ns)
{
    int t = blockIdx.x * 256 + threadIdx.x;
    if (t >= 2 * PIDX) return;
    int h = t >> 15;
    int e = t & (PIDX - 1);
    int b = e >> 10;
    int g = (e >> 5) & 31;
    int r = e & 31;

    const float* A = accum + (long long)h * M;   // split s at +s*TWO_M
    uint4 E[2];
    #pragma unroll
    for (int bb = 0; bb < 2; ++bb) {
        unsigned q[12];
        int j = 0;
        #pragma unroll
        for (int gg = 0; gg < 2; ++gg)
            #pragma unroll
            for (int rr = 0; rr < 2; ++rr)
                #pragma unroll
                for (int c = 0; c < 3; ++c) {
                    int i = c * D3 + ((b + bb) * D + (g + gg)) * D + (r + rr);
                    float v = A[i];
                    for (int s = 1; s < ns; ++s) v += A[i + (long long)s * TWO_M];
                    v = fminf(fmaxf(v, 0.0f), 1.0f);
                    q[j++] = (unsigned)(v * 1023.0f + 0.5f);
                }
        E[bb].x = q[0] | (q[1]  << 10) | (q[2]  << 20);
        E[bb].y = q[3] | (q[4]  << 10) | (q[5]  << 20);
        E[bb].z = q[6] | (q[7]  << 10) | (q[8]  << 20);
        E[bb].w = q[9] | (q[10] << 10) | (q[11] << 20);
    }
    packed[2 * t]     = E[0];
    packed[2 * t + 1] = E[1];
}

// ---------------------------------------------------------------------------
// Trilinear apply for 4 independent pixels: all 8 gathers (one 64 B line per
// pixel) issued before any unpack -> 8 loads in flight per dependent stage.
// ---------------------------------------------------------------------------
__device__ __forceinline__ void apply4(const u4* __restrict__ L,
                                       const float* r, const float* g, const float* b,
                                       float* pr, float* pg, float* pb)
{
    u4 E0[4], E1[4];
    float fr[4], fg[4], fb[4];
    #pragma unroll
    for (int i = 0; i < 4; ++i) {
        float xr = r[i] * 32.0f, xg = g[i] * 32.0f, xb = b[i] * 32.0f;
        int r0 = min(max((int)xr, 0), 31);   // inputs >= 0: trunc == floor
        int g0 = min(max((int)xg, 0), 31);
        int b0 = min(max((int)xb, 0), 31);
        fr[i] = xr - (float)r0;
        fg[i] = xg - (float)g0;
        fb[i] = xb - (float)b0;
        int idx = (b0 << 10) + (g0 << 5) + r0;
        E0[i] = L[2 * idx];          // b-level b0
        E1[i] = L[2 * idx + 1];      // b-level b0+1 (same 64 B line)
    }
    const float inv = 1.0f / 1023.0f;
    #pragma unroll
    for (int i = 0; i < 4; ++i) {
        float w00 = (1.0f - fg[i]) * (1.0f - fr[i]);
        float w01 = (1.0f - fg[i]) * fr[i];
        float w10 = fg[i] * (1.0f - fr[i]);
        float w11 = fg[i] * fr[i];
        float wb0 = 1.0f - fb[i], wb1 = fb[i];

        float sr, sg, sb;
        {
            float a00 = wb0 * w00, a01 = wb0 * w01, a10 = wb0 * w10, a11 = wb0 * w11;
            sr = a00 * (float)( E0[i].x        & 1023) + a01 * (float)( E0[i].y        & 1023)
               + a10 * (float)( E0[i].z        & 1023) + a11 * (float)( E0[i].w        & 1023);
            sg = a00 * (float)((E0[i].x >> 10) & 1023) + a01 * (float)((E0[i].y >> 10) & 1023)
               + a10 * (float)((E0[i].z >> 10) & 1023) + a11 * (float)((E0[i].w >> 10) & 1023);
            sb = a00 * (float)((E0[i].x >> 20) & 1023) + a01 * (float)((E0[i].y >> 20) & 1023)
               + a10 * (float)((E0[i].z >> 20) & 1023) + a11 * (float)((E0[i].w >> 20) & 1023);
        }
        {
            float a00 = wb1 * w00, a01 = wb1 * w01, a10 = wb1 * w10, a11 = wb1 * w11;
            sr += a00 * (float)( E1[i].x        & 1023) + a01 * (float)( E1[i].y        & 1023)
                + a10 * (float)( E1[i].z        & 1023) + a11 * (float)( E1[i].w        & 1023);
            sg += a00 * (float)((E1[i].x >> 10) & 1023) + a01 * (float)((E1[i].y >> 10) & 1023)
                + a10 * (float)((E1[i].z >> 10) & 1023) + a11 * (float)((E1[i].w >> 10) & 1023);
            sb += a00 * (float)((E1[i].x >> 20) & 1023) + a01 * (float)((E1[i].y >> 20) & 1023)
                + a10 * (float)((E1[i].z >> 20) & 1023) + a11 * (float)((E1[i].w >> 20) & 1023);
        }
        pr[i] = sr * inv; pg[i] = sg * inv; pb[i] = sb * inv;
    }
}

// ---------------------------------------------------------------------------
// Kernel C: fused  I_f = apply(CL1, apply(CL0, gt)) — 2 line-touches/pixel.
// 4 pixels/thread via float4 non-temporal stream I/O (keeps the 2 MB LUT
// L2-resident against the 199 MB gt/out stream) + ILP-4 gather chains.
// ---------------------------------------------------------------------------
__global__ __launch_bounds__(256) void fused_apply_kernel(
    const float* __restrict__ gt,       // [3][H][W]
    const u4* __restrict__ packed,      // [2][PIDX][2]
    float* __restrict__ out)            // [3][H][W]
{
    int q = blockIdx.x * 256 + threadIdx.x;
    if (q >= QPIX) return;

    const f4* g4 = (const f4*)gt;
    f4 Rv = __builtin_nontemporal_load(g4 + q);
    f4 Gv = __builtin_nontemporal_load(g4 + q + QPIX);
    f4 Bv = __builtin_nontemporal_load(g4 + q + 2 * QPIX);

    float r0[4] = {Rv.x, Rv.y, Rv.z, Rv.w};
    float g0[4] = {Gv.x, Gv.y, Gv.z, Gv.w};
    float b0[4] = {Bv.x, Bv.y, Bv.z, Bv.w};
    float r1[4], g1[4], b1[4], r2[4], g2[4], b2[4];

    apply4(packed,       r0, g0, b0, r1, g1, b1);
    apply4(packed + PU4, r1, g1, b1, r2, g2, b2);

    f4 Ro = {r2[0], r2[1], r2[2], r2[3]};
    f4 Go = {g2[0], g2[1], g2[2], g2[3]};
    f4 Bo = {b2[0], b2[1], b2[2], b2[3]};
    f4* o4 = (f4*)out;
    __builtin_nontemporal_store(Ro, o4 + q);
    __builtin_nontemporal_store(Go, o4 + q + QPIX);
    __builtin_nontemporal_store(Bo, o4 + q + 2 * QPIX);
}

extern "C" void kernel_launch(void* const* d_in, const int* in_sizes, int n_in,
                              void* d_out, int out_size, void* d_ws, size_t ws_size,
                              hipStream_t stream)
{
    const float* gt  = (const float*)d_in[0];
    const float* lut = (const float*)d_in[1];
    // d_in[2] / d_in[3] (L0, L1) are dead code in the reference.
    float* out = (float*)d_out;

    const size_t packed_bytes = (size_t)2 * PU4 * sizeof(uint4);            // 2 MiB
    size_t a2 = ((size_t)2 * TWO_M * sizeof(float) + 31) & ~(size_t)31;     // 1,724,992
    size_t a1 = ((size_t)1 * TWO_M * sizeof(float) + 31) & ~(size_t)31;     //   862,496
    int ns; size_t poff;
    if (ws_size >= a2 + packed_bytes) { ns = 2; poff = a2; }
    else                              { ns = 1; poff = a1; }

    float* accum  = (float*)d_ws;
    u4*    packed = (u4*)((char*)d_ws + poff);

    if (ns == 2)
        reduce_kernel<2><<<dim3(2 * 2 * HB), dim3(256), 0, stream>>>(lut, accum);
    else
        reduce_kernel<1><<<dim3(1 * 2 * HB), dim3(256), 0, stream>>>(lut, accum);

    pack_kernel<<<dim3((2 * PIDX + 255) / 256), dim3(256), 0, stream>>>(
        accum, (uint4*)packed, ns);
    fused_apply_kernel<<<dim3((QPIX + 255) / 256), dim3(256), 0, stream>>>(gt, packed, out);
}